// Round 7
// baseline (277.686 us; speedup 1.0000x reference)
//
#include <hip/hip_runtime.h>
#include <hip/hip_bf16.h>

typedef __bf16 bf16;
typedef __bf16 bf16x4 __attribute__((ext_vector_type(4)));
typedef __bf16 bf16x8 __attribute__((ext_vector_type(8)));
typedef float f32x4 __attribute__((ext_vector_type(4)));

#define MFMA(a, b, c) __builtin_amdgcn_mfma_f32_16x16x32_bf16(a, b, c, 0, 0, 0)

__device__ inline f32x4 zf4() { return f32x4{0.f, 0.f, 0.f, 0.f}; }

constexpr int Tc = 16, Hc = 56, Wc = 56, Cc = 128, NHc = 4, HDc = 32;
constexpr int VOL = 392;                 // 8*7*7 tokens per window
constexpr int STc = 4, SHc = 3, SWc = 3; // shift
constexpr int TWIN = 256;                // total windows (B * 128)
constexpr int MTOT = TWIN * VOL;         // 100352 tokens
constexpr int QSZ = TWIN * NHc * VOL * HDc;
constexpr int BMT_N = 8 * 4 * 400 * 416; // [pat][head][row][col] bias+mask table

__device__ inline bf16x8 zero8() {
    bf16x8 z;
#pragma unroll
    for (int j = 0; j < 8; ++j) z[j] = (bf16)0.0f;
    return z;
}

__device__ inline f32x4 up4(bf16x4 b) {
    f32x4 r;
#pragma unroll
    for (int j = 0; j < 4; ++j) r[j] = (float)b[j];
    return r;
}

__device__ inline int cls_of(int v, int pt, int ph, int pw) {
    int tt = v / 49, rem = v % 49, hh = rem / 7, ww = rem % 7;
    int ct = pt ? (tt < 4 ? 1 : 2) : 0;
    int ch = ph ? (hh < 4 ? 1 : 2) : 0;
    int cw = pw ? (ww < 4 ? 1 : 2) : 0;
    return ct * 9 + ch * 3 + cw;
}

// ---------------------------------------------------------------------------
// Kernel 0: fused prep. Blocks 0..64: fp32->bf16 param cvt.
// Blocks 65..864: bias+mask table bmt[pat8][head4][row400][col416] bf16 =
//   (rpb + mask)*log2e; pad col -> -144 (exp2 ~ 0), pad row -> 0.
// ---------------------------------------------------------------------------
__global__ void prep_kernel(const float* __restrict__ wq, const float* __restrict__ bq,
                            const float* __restrict__ wp, const float* __restrict__ bp,
                            const float* __restrict__ rpb,
                            bf16* __restrict__ wqb, bf16* __restrict__ bqb,
                            bf16* __restrict__ wpb, bf16* __restrict__ bpb,
                            bf16* __restrict__ bmt) {
    const int blk = blockIdx.x, tid = threadIdx.x;
    if (blk < 65) {
        int i = blk * 256 + tid;
        const float* s; bf16* d; int off;
        if (i < 12288)       { s = wq; d = wqb; off = i; }
        else if (i < 12384)  { s = bq; d = bqb; off = i - 12288; }
        else if (i < 16480)  { s = wp; d = wpb; off = i - 12384; }
        else if (i < 16512)  { s = bp; d = bpb; off = i - 16480; }
        else return;
        f32x4 v = *(const f32x4*)(s + (size_t)off * 4);
        bf16x4 o;
#pragma unroll
        for (int j = 0; j < 4; ++j) o[j] = (bf16)v[j];
        *(bf16x4*)(d + (size_t)off * 4) = o;
        return;
    }
    // bias blocks: bb = (pat, head, rowchunk of 16)
    __shared__ unsigned char clsc[392];
    int bb = blk - 65;
    int pat = bb / 100, rem = bb % 100;
    int head = rem / 25, rc = rem % 25;
    int pt = (pat >> 2) & 1, ph = (pat >> 1) & 1, pw = pat & 1;
    for (int v = tid; v < 392; v += 256) clsc[v] = (unsigned char)cls_of(v, pt, ph, pw);
    __syncthreads();
    bf16* dst = bmt + ((size_t)(pat * NHc + head) * 400 + rc * 16) * 416;
    for (int idx = tid; idx < 16 * 104; idx += 256) {
        int lr = idx / 104, c4 = idx % 104;
        int row = rc * 16 + lr;
        bf16x4 o;
        if (row >= VOL) {
#pragma unroll
            for (int j = 0; j < 4; ++j) o[j] = (bf16)0.f;
        } else {
            int rcls = clsc[row];
            const float* brow = rpb + (size_t)(head * VOL + row) * VOL;
#pragma unroll
            for (int j = 0; j < 4; ++j) {
                int col = c4 * 4 + j;
                float v;
                if (col >= VOL) v = -144.0f;
                else {
                    v = brow[col] * 1.4426950408889634f;
                    if (clsc[col] != rcls) v -= 144.0f;
                }
                o[j] = (bf16)v;
            }
        }
        *(bf16x4*)(dst + (size_t)lr * 416 + c4 * 4) = o;
    }
}

// ---------------------------------------------------------------------------
// Kernel 1: QKV projection (roll+partition fused gather, C^T-layout epilogue).
// Epilogue split into two 192-col phases -> LDS 44 KB -> 3 blocks/CU.
// (4 blocks/CU thrashes L2: +2.4x fabric traffic. 3 is the sweet spot.)
// q pre-scaled by log2(e)/sqrt(32).
// ---------------------------------------------------------------------------
__global__ __launch_bounds__(256, 3)
void qkv_kernel(const float* __restrict__ x, const bf16* __restrict__ wq,
                const bf16* __restrict__ bq, bf16* __restrict__ qws,
                bf16* __restrict__ kws, bf16* __restrict__ vws) {
    __shared__ bf16 As[64][136];
    __shared__ bf16 Cs[64][204];   // 204: 8B-aligned rows (408B), 192 cols + pad
    __shared__ unsigned int rb[64];
    __shared__ unsigned int rbw[64];
    const int tid = threadIdx.x;
    const int m0 = blockIdx.x * 64;

    if (tid < 64) {
        int g = m0 + tid;
        int win = g / VOL, tok = g % VOL;
        int b = win >> 7, wi = win & 127;
        int wt_i = wi >> 6, wh_i = (wi >> 3) & 7, ww_i = wi & 7;
        int tt = tok / 49, r2 = tok % 49, hh = r2 / 7, ww2 = r2 % 7;
        int t = wt_i * 8 + tt + STc; if (t >= Tc) t -= Tc;
        int h = wh_i * 7 + hh + SHc; if (h >= Hc) h -= Hc;
        int w = ww_i * 7 + ww2 + SWc; if (w >= Wc) w -= Wc;
        rb[tid] = (unsigned int)((((b * Tc + t) * Hc + h) * Wc + w) * Cc * 4);
        rbw[tid] = (unsigned int)((win << 9) | tok);
    }
    __syncthreads();

    for (int idx = tid; idx < 64 * 32; idx += 256) {
        int r = idx >> 5, c = idx & 31;
        const float* src = (const float*)((const char*)x + rb[r]) + c * 4;
        f32x4 v = *(const f32x4*)src;
        bf16x4 o;
#pragma unroll
        for (int j = 0; j < 4; ++j) o[j] = (bf16)v[j];
        *(bf16x4*)(&As[r][c * 4]) = o;
    }
    __syncthreads();

    const int wid = tid >> 6, lane = tid & 63;
    const int quad = lane >> 4, l15 = lane & 15;
    const int nbase = wid * 96;

    f32x4 acc[6][4];  // [mt = W-col tile][nt = row tile]
#pragma unroll
    for (int mt = 0; mt < 6; ++mt)
#pragma unroll
        for (int nt = 0; nt < 4; ++nt) acc[mt][nt] = zf4();

#pragma unroll
    for (int ko = 0; ko < 4; ++ko) {
        bf16x8 xf[4];  // B-operand: x rows
#pragma unroll
        for (int nt = 0; nt < 4; ++nt)
            xf[nt] = *(const bf16x8*)(&As[nt * 16 + l15][ko * 32 + quad * 8]);
#pragma unroll
        for (int mt = 0; mt < 6; ++mt) {
            bf16x8 wf = *(const bf16x8*)(wq + (size_t)(nbase + mt * 16 + l15) * Cc + ko * 32 + quad * 8);
#pragma unroll
            for (int nt = 0; nt < 4; ++nt)
                acc[mt][nt] = MFMA(wf, xf[nt], acc[mt][nt]);  // C^T: m=col, n=row
        }
    }

    // Two-phase epilogue: phase 0 = cols [0,192) (waves 0,1), phase 1 = [192,384).
#pragma unroll 1
    for (int phase = 0; phase < 2; ++phase) {
        if ((wid >> 1) == phase) {
#pragma unroll
            for (int mt = 0; mt < 6; ++mt) {
                int colbase = nbase + mt * 16 + quad * 4;
                int lc = colbase - phase * 192;   // in [0,192)
                bf16x4 bc = *(const bf16x4*)(bq + colbase);
                float scale = (colbase < 128) ? 0.25505653942f : 1.0f;  // log2e/sqrt(32) on q
#pragma unroll
                for (int nt = 0; nt < 4; ++nt) {
                    bf16x4 o;
#pragma unroll
                    for (int r = 0; r < 4; ++r)
                        o[r] = (bf16)((acc[mt][nt][r] + (float)bc[r]) * scale);
                    *(bf16x4*)(&Cs[nt * 16 + l15][lc]) = o;
                }
            }
        }
        __syncthreads();
        // store 64 rows x 6 head-slices of 32 cols each (same global pattern as r0)
        for (int u = tid; u < 64 * 6; u += 256) {
            int row = u / 6, s = u - row * 6;
            int gs = phase * 6 + s;   // 0..3 q.h, 4..7 k.h, 8..11 v.h
            bf16* basep = (gs < 4) ? qws : (gs < 8) ? kws : vws;
            int head = gs & 3;
            unsigned int p = rbw[row];
            int win = p >> 9, tok = p & 511;
            size_t off = ((size_t)(win * NHc + head) * VOL + tok) * HDc;
#pragma unroll
            for (int c = 0; c < 4; ++c) {
                bf16x4 lo = *(const bf16x4*)(&Cs[row][s * 32 + c * 8]);
                bf16x4 hi = *(const bf16x4*)(&Cs[row][s * 32 + c * 8 + 4]);
                *(bf16x8*)(basep + off + c * 8) = __builtin_shufflevector(lo, hi, 0, 1, 2, 3, 4, 5, 6, 7);
            }
        }
        __syncthreads();
    }
}

// ---------------------------------------------------------------------------
// Kernel 2: windowed attention, S^T formulation, pattern bias table.
// SINGLE k-sweep, 4 q-tile streams per wave (tiles wid, wid+8, wid+16, [24 on
// wave 0]): kf/vf LDS fragments loaded ONCE per kt and shared by all streams
// (-33% b128 LDS reads vs the 2-pass version). 2 rotating P buffers per wave;
// interleave qkA qkB pvA qkC pvB qkD pvC pvD keeps every P write->read pair
// separated by a full qk call (same-wave in-order DS => WAR-safe).
// ---------------------------------------------------------------------------
__global__ __launch_bounds__(512, 4)
void attn_kernel(const bf16* __restrict__ qws, const bf16* __restrict__ kws,
                 const bf16* __restrict__ vws, const bf16* __restrict__ bmt,
                 bf16* __restrict__ aows) {
    __shared__ bf16 Kl[400][40];      // rows 392..399 zero (kt12 is half-tile)
    __shared__ bf16 Vt[32][424];      // V transposed
    __shared__ bf16 Pb[8][2][16][40]; // per-wave, 2 rotating P buffers

    const int tid = threadIdx.x;
    const int win = blockIdx.x >> 2, head = blockIdx.x & 3;
    const int wi = win & 127;
    const int wt_i = wi >> 6, wh_i = (wi >> 3) & 7, ww_i = wi & 7;
    const int pat = ((wt_i == 1) << 2) | ((wh_i == 7) << 1) | (ww_i == 7);

    const bf16* Qg = qws + (size_t)(win * NHc + head) * VOL * HDc;
    const bf16* Kg = kws + (size_t)(win * NHc + head) * VOL * HDc;
    const bf16* Vg = vws + (size_t)(win * NHc + head) * VOL * HDc;
    const bf16* Bg = bmt + (size_t)(pat * NHc + head) * 400 * 416;

    for (int idx = tid; idx < 400 * 4; idx += 512) {
        int tok = idx >> 2, c = idx & 3;
        bf16x8 v = zero8();
        if (tok < VOL) v = *(const bf16x8*)(Kg + tok * HDc + c * 8);
        *(bf16x8*)(&Kl[tok][c * 8]) = v;
    }
    if (tid < 416) {  // V transpose: b64 chunks of 4 toks
        int c = tid & 3, tok4 = (tid >> 2) * 4;
        bf16x8 rr[4];
#pragma unroll
        for (int i = 0; i < 4; ++i)
            rr[i] = (tok4 + i < VOL) ? *(const bf16x8*)(Vg + (tok4 + i) * HDc + c * 8) : zero8();
#pragma unroll
        for (int j = 0; j < 8; ++j) {
            bf16x4 wv;
            wv[0] = rr[0][j]; wv[1] = rr[1][j]; wv[2] = rr[2][j]; wv[3] = rr[3][j];
            *(bf16x4*)(&Vt[c * 8 + j][tok4]) = wv;
        }
    }
    __syncthreads();

    const int wid = tid >> 6, lane = tid & 63;
    const int quad = lane >> 4, l15 = lane & 15;
    bf16* Pw0 = &Pb[wid][0][0][0];
    bf16* Pw1 = &Pb[wid][1][0][0];
    const bool hasD = (wid == 0);

    // stream q-tile bases: A,B,C rows all < 384 (no clamp); D rows 384..399.
    const int qbA = wid * 16, qbB = qbA + 128, qbC = qbA + 256, qbD = 384;
    const bf16x8 qfA = *(const bf16x8*)(Qg + (size_t)(qbA + l15) * HDc + quad * 8);
    const bf16x8 qfB = *(const bf16x8*)(Qg + (size_t)(qbB + l15) * HDc + quad * 8);
    const bf16x8 qfC = *(const bf16x8*)(Qg + (size_t)(qbC + l15) * HDc + quad * 8);
    bf16x8 qfD;
    const int brA = (qbA + l15) * 416, brB = (qbB + l15) * 416;
    const int brC = (qbC + l15) * 416, brD = (qbD + l15) * 416;

    f32x4 oA0 = zf4(), oA1 = zf4(), oB0 = zf4(), oB1 = zf4();
    f32x4 oC0 = zf4(), oC1 = zf4(), oD0 = zf4(), oD1 = zf4();
    float lsA = 0.f, lsB = 0.f, lsC = 0.f, lsD = 0.f;

    bf16x4 nbA0 = *(const bf16x4*)(Bg + brA + quad * 4);
    bf16x4 nbA1 = *(const bf16x4*)(Bg + brA + 16 + quad * 4);
    bf16x4 nbB0 = *(const bf16x4*)(Bg + brB + quad * 4);
    bf16x4 nbB1 = *(const bf16x4*)(Bg + brB + 16 + quad * 4);
    bf16x4 nbC0 = *(const bf16x4*)(Bg + brC + quad * 4);
    bf16x4 nbC1 = *(const bf16x4*)(Bg + brC + 16 + quad * 4);
    bf16x4 nbD0, nbD1;
    if (hasD) {
        int qrD = qbD + l15; if (qrD >= VOL) qrD = VOL - 1;
        qfD = *(const bf16x8*)(Qg + (size_t)qrD * HDc + quad * 8);
        nbD0 = *(const bf16x4*)(Bg + brD + quad * 4);
        nbD1 = *(const bf16x4*)(Bg + brD + 16 + quad * 4);
    }

    // full 32-k tile: S^T MFMA pair + exp2 + P write; prefetch bias one kt ahead
    auto qk = [&](const bf16x8& kf0, const bf16x8& kf1, const bf16x8& qf,
                  bf16x4& nb0, bf16x4& nb1, int br, float& ls, bf16* Pw, int kb) {
        f32x4 c0 = up4(nb0), c1 = up4(nb1);
        if (kb < 384) {
            nb0 = *(const bf16x4*)(Bg + br + kb + 32 + quad * 4);
            nb1 = *(const bf16x4*)(Bg + br + kb + 48 + quad * 4);
        }
        f32x4 s0 = MFMA(kf0, qf, c0);
        f32x4 s1 = MFMA(kf1, qf, c1);
        bf16x4 p0, p1;
        float la = 0.f;
#pragma unroll
        for (int r = 0; r < 4; ++r) {
            float e0 = __builtin_amdgcn_exp2f(s0[r]);
            float e1 = __builtin_amdgcn_exp2f(s1[r]);
            p0[r] = (bf16)e0; p1[r] = (bf16)e1; la += e0 + e1;
        }
        ls += la;
        *(bf16x4*)(Pw + l15 * 40 + quad * 4) = p0;
        *(bf16x4*)(Pw + l15 * 40 + 16 + quad * 4) = p1;
    };
    // kt12 half-tile: only k 384..399 real; second half of P zeroed
    auto qkh = [&](const bf16x8& kf0, const bf16x8& qf, bf16x4& nb0, float& ls, bf16* Pw) {
        f32x4 c0 = up4(nb0);
        f32x4 s0 = MFMA(kf0, qf, c0);
        bf16x4 p0, z4;
        float la = 0.f;
#pragma unroll
        for (int r = 0; r < 4; ++r) {
            float e0 = __builtin_amdgcn_exp2f(s0[r]);
            p0[r] = (bf16)e0; la += e0; z4[r] = (bf16)0.f;
        }
        ls += la;
        *(bf16x4*)(Pw + l15 * 40 + quad * 4) = p0;
        *(bf16x4*)(Pw + l15 * 40 + 16 + quad * 4) = z4;
    };
    auto pv = [&](bf16* Pw, const bf16x8& vf0, const bf16x8& vf1, f32x4& o0, f32x4& o1) {
        bf16x8 pf = *(const bf16x8*)(Pw + l15 * 40 + quad * 8);
        o0 = MFMA(vf0, pf, o0);
        o1 = MFMA(vf1, pf, o1);
    };

#pragma unroll 1
    for (int kt = 0; kt < 12; ++kt) {
        const int kb = kt * 32;
        bf16x8 kf0 = *(const bf16x8*)(&Kl[kb + l15][quad * 8]);
        bf16x8 kf1 = *(const bf16x8*)(&Kl[kb + 16 + l15][quad * 8]);
        bf16x8 vf0 = *(const bf16x8*)(&Vt[l15][kb + quad * 8]);
        bf16x8 vf1 = *(const bf16x8*)(&Vt[16 + l15][kb + quad * 8]);
        qk(kf0, kf1, qfA, nbA0, nbA1, brA, lsA, Pw0, kb);
        qk(kf0, kf1, qfB, nbB0, nbB1, brB, lsB, Pw1, kb);
        pv(Pw0, vf0, vf1, oA0, oA1);
        qk(kf0, kf1, qfC, nbC0, nbC1, brC, lsC, Pw0, kb);
        pv(Pw1, vf0, vf1, oB0, oB1);
        if (hasD) qk(kf0, kf1, qfD, nbD0, nbD1, brD, lsD, Pw1, kb);
        pv(Pw0, vf0, vf1, oC0, oC1);
        if (hasD) pv(Pw1, vf0, vf1, oD0, oD1);
    }
    {   // kt = 12 (kb=384): half-tile
        bf16x8 kf0 = *(const bf16x8*)(&Kl[384 + l15][quad * 8]);
        bf16x8 vf0 = *(const bf16x8*)(&Vt[l15][384 + quad * 8]);
        bf16x8 vf1 = *(const bf16x8*)(&Vt[16 + l15][384 + quad * 8]);
        qkh(kf0, qfA, nbA0, lsA, Pw0);
        qkh(kf0, qfB, nbB0, lsB, Pw1);
        pv(Pw0, vf0, vf1, oA0, oA1);
        qkh(kf0, qfC, nbC0, lsC, Pw0);
        pv(Pw1, vf0, vf1, oB0, oB1);
        if (hasD) qkh(kf0, qfD, nbD0, lsD, Pw1);
        pv(Pw0, vf0, vf1, oC0, oC1);
        if (hasD) pv(Pw1, vf0, vf1, oD0, oD1);
    }

    auto fin = [&](float ls, const f32x4& o0, const f32x4& o1, int qb) {
        ls += __shfl_xor(ls, 16); ls += __shfl_xor(ls, 32);
        if (qb + l15 < VOL) {
            float inv = 1.f / ls;
            bf16x4 w0, w1;
#pragma unroll
            for (int r = 0; r < 4; ++r) { w0[r] = (bf16)(o0[r] * inv); w1[r] = (bf16)(o1[r] * inv); }
            bf16* dst = aows + ((size_t)win * VOL + qb + l15) * Cc + head * HDc;
            *(bf16x4*)(dst + quad * 4) = w0;
            *(bf16x4*)(dst + 16 + quad * 4) = w1;
        }
    };
    fin(lsA, oA0, oA1, qbA);
    fin(lsB, oB0, oB1, qbB);
    fin(lsC, oC0, oC1, qbC);
    if (hasD) fin(lsD, oD0, oD1, qbD);
}

// ---------------------------------------------------------------------------
// Kernel 3: output projection (C^T epilogue: f32x4 b128 LDS writes) +
// un-partition + roll-back scatter, fp32 out.
// ---------------------------------------------------------------------------
__global__ __launch_bounds__(256, 2)
void proj_kernel(const bf16* __restrict__ aows, const bf16* __restrict__ wp,
                 const bf16* __restrict__ bp, float* __restrict__ out) {
    __shared__ bf16 As[64][136];
    __shared__ float Csf[64][132];
    __shared__ unsigned int rbo[64];
    const int tid = threadIdx.x;
    const int m0 = blockIdx.x * 64;

    if (tid < 64) {
        int g = m0 + tid;
        int win = g / VOL, tok = g % VOL;
        int b = win >> 7, wi = win & 127;
        int wt_i = wi >> 6, wh_i = (wi >> 3) & 7, ww_i = wi & 7;
        int tt = tok / 49, r2 = tok % 49, hh = r2 / 7, ww2 = r2 % 7;
        int t = wt_i * 8 + tt + STc; if (t >= Tc) t -= Tc;
        int h = wh_i * 7 + hh + SHc; if (h >= Hc) h -= Hc;
        int w = ww_i * 7 + ww2 + SWc; if (w >= Wc) w -= Wc;
        rbo[tid] = (unsigned int)((((b * Tc + t) * Hc + h) * Wc + w) * Cc * 4);
    }
    for (int idx = tid; idx < 64 * 16; idx += 256) {
        int r = idx >> 4, c = idx & 15;
        *(bf16x8*)(&As[r][c * 8]) = *(const bf16x8*)(aows + (size_t)(m0 + r) * Cc + c * 8);
    }
    __syncthreads();

    const int wid = tid >> 6, lane = tid & 63;
    const int quad = lane >> 4, l15 = lane & 15;

    f32x4 acc[8];  // mt over 128 output cols; rows = wid*16..+15
#pragma unroll
    for (int mt = 0; mt < 8; ++mt) acc[mt] = zf4();

#pragma unroll
    for (int ko = 0; ko < 4; ++ko) {
        bf16x8 xf = *(const bf16x8*)(&As[wid * 16 + l15][ko * 32 + quad * 8]);
#pragma unroll
        for (int mt = 0; mt < 8; ++mt) {
            bf16x8 wf = *(const bf16x8*)(wp + (size_t)(mt * 16 + l15) * Cc + ko * 32 + quad * 8);
            acc[mt] = MFMA(wf, xf, acc[mt]);  // C^T: m=col, n=row
        }
    }
#pragma unroll
    for (int mt = 0; mt < 8; ++mt) {
        int colbase = mt * 16 + quad * 4;
        bf16x4 bc = *(const bf16x4*)(bp + colbase);
        f32x4 o;
#pragma unroll
        for (int r = 0; r < 4; ++r) o[r] = acc[mt][r] + (float)bc[r];
        *(f32x4*)(&Csf[wid * 16 + l15][colbase]) = o;
    }
    __syncthreads();

    for (int idx = tid; idx < 64 * 32; idx += 256) {
        int row = idx >> 5, ch = idx & 31;
        float* dst = (float*)((char*)out + rbo[row]) + ch * 4;
        *(f32x4*)dst = *(const f32x4*)(&Csf[row][ch * 4]);
    }
}

extern "C" void kernel_launch(void* const* d_in, const int* in_sizes, int n_in,
                              void* d_out, int out_size, void* d_ws, size_t ws_size,
                              hipStream_t stream) {
    const float* x    = (const float*)d_in[0];
    const float* wqf  = (const float*)d_in[1];
    const float* bqf  = (const float*)d_in[2];
    const float* wpf  = (const float*)d_in[3];
    const float* bpf  = (const float*)d_in[4];
    const float* rpbf = (const float*)d_in[5];
    float* out = (float*)d_out;

    bf16* wqb  = (bf16*)d_ws;              // 49152
    bf16* bqb  = wqb + 49152;              // 384
    bf16* wpb  = bqb + 384;                // 16384
    bf16* bpb  = wpb + 16384;              // 128
    bf16* bmt  = bpb + 128;                // BMT_N = 5,324,800
    bf16* qws  = bmt + BMT_N;
    bf16* kws  = qws + QSZ;
    bf16* vws  = kws + QSZ;
    bf16* aows = vws + QSZ;

    hipLaunchKernelGGL(prep_kernel, dim3(865), dim3(256), 0, stream,
                       wqf, bqf, wpf, bpf, rpbf, wqb, bqb, wpb, bpb, bmt);
    hipLaunchKernelGGL(qkv_kernel, dim3(MTOT / 64), dim3(256), 0, stream,
                       x, wqb, bqb, qws, kws, vws);
    hipLaunchKernelGGL(attn_kernel, dim3(TWIN * NHc), dim3(512), 0, stream,
                       qws, kws, vws, bmt, aows);
    hipLaunchKernelGGL(proj_kernel, dim3(MTOT / 64), dim3(256), 0, stream,
                       aows, wpb, bpb, out);
}

// Round 8
// 260.212 us; speedup vs baseline: 1.0672x; 1.0672x over previous
//
#include <hip/hip_runtime.h>
#include <hip/hip_bf16.h>

typedef __bf16 bf16;
typedef __bf16 bf16x4 __attribute__((ext_vector_type(4)));
typedef __bf16 bf16x8 __attribute__((ext_vector_type(8)));
typedef float f32x4 __attribute__((ext_vector_type(4)));

#define MFMA(a, b, c) __builtin_amdgcn_mfma_f32_16x16x32_bf16(a, b, c, 0, 0, 0)

__device__ inline f32x4 zf4() { return f32x4{0.f, 0.f, 0.f, 0.f}; }

constexpr int Tc = 16, Hc = 56, Wc = 56, Cc = 128, NHc = 4, HDc = 32;
constexpr int VOL = 392;                 // 8*7*7 tokens per window
constexpr int STc = 4, SHc = 3, SWc = 3; // shift
constexpr int TWIN = 256;                // total windows (B * 128)
constexpr int MTOT = TWIN * VOL;         // 100352 tokens
constexpr int QSZ = TWIN * NHc * VOL * HDc;
constexpr int BMT_N = 8 * 4 * 400 * 416; // [pat][head][row][col] bias+mask table

__device__ inline bf16x8 zero8() {
    bf16x8 z;
#pragma unroll
    for (int j = 0; j < 8; ++j) z[j] = (bf16)0.0f;
    return z;
}

__device__ inline f32x4 up4(bf16x4 b) {
    f32x4 r;
#pragma unroll
    for (int j = 0; j < 4; ++j) r[j] = (float)b[j];
    return r;
}

__device__ inline int cls_of(int v, int pt, int ph, int pw) {
    int tt = v / 49, rem = v % 49, hh = rem / 7, ww = rem % 7;
    int ct = pt ? (tt < 4 ? 1 : 2) : 0;
    int ch = ph ? (hh < 4 ? 1 : 2) : 0;
    int cw = pw ? (ww < 4 ? 1 : 2) : 0;
    return ct * 9 + ch * 3 + cw;
}

// ---------------------------------------------------------------------------
// Kernel 0: fused prep. Blocks 0..64: fp32->bf16 param cvt.
// Blocks 65..864: bias+mask table bmt[pat8][head4][row400][col416] bf16 =
//   (rpb + mask)*log2e; pad col -> -144 (exp2 ~ 0), pad row -> 0.
// ---------------------------------------------------------------------------
__global__ void prep_kernel(const float* __restrict__ wq, const float* __restrict__ bq,
                            const float* __restrict__ wp, const float* __restrict__ bp,
                            const float* __restrict__ rpb,
                            bf16* __restrict__ wqb, bf16* __restrict__ bqb,
                            bf16* __restrict__ wpb, bf16* __restrict__ bpb,
                            bf16* __restrict__ bmt) {
    const int blk = blockIdx.x, tid = threadIdx.x;
    if (blk < 65) {
        int i = blk * 256 + tid;
        const float* s; bf16* d; int off;
        if (i < 12288)       { s = wq; d = wqb; off = i; }
        else if (i < 12384)  { s = bq; d = bqb; off = i - 12288; }
        else if (i < 16480)  { s = wp; d = wpb; off = i - 12384; }
        else if (i < 16512)  { s = bp; d = bpb; off = i - 16480; }
        else return;
        f32x4 v = *(const f32x4*)(s + (size_t)off * 4);
        bf16x4 o;
#pragma unroll
        for (int j = 0; j < 4; ++j) o[j] = (bf16)v[j];
        *(bf16x4*)(d + (size_t)off * 4) = o;
        return;
    }
    // bias blocks: bb = (pat, head, rowchunk of 16)
    __shared__ unsigned char clsc[392];
    int bb = blk - 65;
    int pat = bb / 100, rem = bb % 100;
    int head = rem / 25, rc = rem % 25;
    int pt = (pat >> 2) & 1, ph = (pat >> 1) & 1, pw = pat & 1;
    for (int v = tid; v < 392; v += 256) clsc[v] = (unsigned char)cls_of(v, pt, ph, pw);
    __syncthreads();
    bf16* dst = bmt + ((size_t)(pat * NHc + head) * 400 + rc * 16) * 416;
    for (int idx = tid; idx < 16 * 104; idx += 256) {
        int lr = idx / 104, c4 = idx % 104;
        int row = rc * 16 + lr;
        bf16x4 o;
        if (row >= VOL) {
#pragma unroll
            for (int j = 0; j < 4; ++j) o[j] = (bf16)0.f;
        } else {
            int rcls = clsc[row];
            const float* brow = rpb + (size_t)(head * VOL + row) * VOL;
#pragma unroll
            for (int j = 0; j < 4; ++j) {
                int col = c4 * 4 + j;
                float v;
                if (col >= VOL) v = -144.0f;
                else {
                    v = brow[col] * 1.4426950408889634f;
                    if (clsc[col] != rcls) v -= 144.0f;
                }
                o[j] = (bf16)v;
            }
        }
        *(bf16x4*)(dst + (size_t)lr * 416 + c4 * 4) = o;
    }
}

// ---------------------------------------------------------------------------
// Kernel 1: QKV projection (roll+partition fused gather, C^T-layout epilogue).
// Epilogue split into two 192-col phases -> LDS 44 KB -> 3 blocks/CU.
// (4 blocks/CU thrashes L2: +2.4x fabric traffic. 3 is the sweet spot.)
// q pre-scaled by log2(e)/sqrt(32).
// ---------------------------------------------------------------------------
__global__ __launch_bounds__(256, 3)
void qkv_kernel(const float* __restrict__ x, const bf16* __restrict__ wq,
                const bf16* __restrict__ bq, bf16* __restrict__ qws,
                bf16* __restrict__ kws, bf16* __restrict__ vws) {
    __shared__ bf16 As[64][136];
    __shared__ bf16 Cs[64][204];   // 204: 8B-aligned rows (408B), 192 cols + pad
    __shared__ unsigned int rb[64];
    __shared__ unsigned int rbw[64];
    const int tid = threadIdx.x;
    const int m0 = blockIdx.x * 64;

    if (tid < 64) {
        int g = m0 + tid;
        int win = g / VOL, tok = g % VOL;
        int b = win >> 7, wi = win & 127;
        int wt_i = wi >> 6, wh_i = (wi >> 3) & 7, ww_i = wi & 7;
        int tt = tok / 49, r2 = tok % 49, hh = r2 / 7, ww2 = r2 % 7;
        int t = wt_i * 8 + tt + STc; if (t >= Tc) t -= Tc;
        int h = wh_i * 7 + hh + SHc; if (h >= Hc) h -= Hc;
        int w = ww_i * 7 + ww2 + SWc; if (w >= Wc) w -= Wc;
        rb[tid] = (unsigned int)((((b * Tc + t) * Hc + h) * Wc + w) * Cc * 4);
        rbw[tid] = (unsigned int)((win << 9) | tok);
    }
    __syncthreads();

    for (int idx = tid; idx < 64 * 32; idx += 256) {
        int r = idx >> 5, c = idx & 31;
        const float* src = (const float*)((const char*)x + rb[r]) + c * 4;
        f32x4 v = *(const f32x4*)src;
        bf16x4 o;
#pragma unroll
        for (int j = 0; j < 4; ++j) o[j] = (bf16)v[j];
        *(bf16x4*)(&As[r][c * 4]) = o;
    }
    __syncthreads();

    const int wid = tid >> 6, lane = tid & 63;
    const int quad = lane >> 4, l15 = lane & 15;
    const int nbase = wid * 96;

    f32x4 acc[6][4];  // [mt = W-col tile][nt = row tile]
#pragma unroll
    for (int mt = 0; mt < 6; ++mt)
#pragma unroll
        for (int nt = 0; nt < 4; ++nt) acc[mt][nt] = zf4();

#pragma unroll
    for (int ko = 0; ko < 4; ++ko) {
        bf16x8 xf[4];  // B-operand: x rows
#pragma unroll
        for (int nt = 0; nt < 4; ++nt)
            xf[nt] = *(const bf16x8*)(&As[nt * 16 + l15][ko * 32 + quad * 8]);
#pragma unroll
        for (int mt = 0; mt < 6; ++mt) {
            bf16x8 wf = *(const bf16x8*)(wq + (size_t)(nbase + mt * 16 + l15) * Cc + ko * 32 + quad * 8);
#pragma unroll
            for (int nt = 0; nt < 4; ++nt)
                acc[mt][nt] = MFMA(wf, xf[nt], acc[mt][nt]);  // C^T: m=col, n=row
        }
    }

    // Two-phase epilogue: phase 0 = cols [0,192) (waves 0,1), phase 1 = [192,384).
#pragma unroll 1
    for (int phase = 0; phase < 2; ++phase) {
        if ((wid >> 1) == phase) {
#pragma unroll
            for (int mt = 0; mt < 6; ++mt) {
                int colbase = nbase + mt * 16 + quad * 4;
                int lc = colbase - phase * 192;   // in [0,192)
                bf16x4 bc = *(const bf16x4*)(bq + colbase);
                float scale = (colbase < 128) ? 0.25505653942f : 1.0f;  // log2e/sqrt(32) on q
#pragma unroll
                for (int nt = 0; nt < 4; ++nt) {
                    bf16x4 o;
#pragma unroll
                    for (int r = 0; r < 4; ++r)
                        o[r] = (bf16)((acc[mt][nt][r] + (float)bc[r]) * scale);
                    *(bf16x4*)(&Cs[nt * 16 + l15][lc]) = o;
                }
            }
        }
        __syncthreads();
        // store 64 rows x 6 head-slices of 32 cols each (same global pattern as r0)
        for (int u = tid; u < 64 * 6; u += 256) {
            int row = u / 6, s = u - row * 6;
            int gs = phase * 6 + s;   // 0..3 q.h, 4..7 k.h, 8..11 v.h
            bf16* basep = (gs < 4) ? qws : (gs < 8) ? kws : vws;
            int head = gs & 3;
            unsigned int p = rbw[row];
            int win = p >> 9, tok = p & 511;
            size_t off = ((size_t)(win * NHc + head) * VOL + tok) * HDc;
#pragma unroll
            for (int c = 0; c < 4; ++c) {
                bf16x4 lo = *(const bf16x4*)(&Cs[row][s * 32 + c * 8]);
                bf16x4 hi = *(const bf16x4*)(&Cs[row][s * 32 + c * 8 + 4]);
                *(bf16x8*)(basep + off + c * 8) = __builtin_shufflevector(lo, hi, 0, 1, 2, 3, 4, 5, 6, 7);
            }
        }
        __syncthreads();
    }
}

// ---------------------------------------------------------------------------
// Kernel 2: windowed attention, S^T formulation, pattern bias table.
// SINGLE k-sweep, 4 q-tile streams per wave. Launch bounds (512,2): the
// (512,4) variant capped VGPRs at 64 -> ~110-reg state spilled to scratch
// (+19MB WRITE, dur 70.7->85.5). Cap >=128 removes spill; LDS (79.9KB)
// still allows 2 blocks/CU, VGPR<=128 sustains 4 waves/SIMD -> same occ.
// ---------------------------------------------------------------------------
__global__ __launch_bounds__(512, 2)
void attn_kernel(const bf16* __restrict__ qws, const bf16* __restrict__ kws,
                 const bf16* __restrict__ vws, const bf16* __restrict__ bmt,
                 bf16* __restrict__ aows) {
    __shared__ bf16 Kl[400][40];      // rows 392..399 zero (kt12 is half-tile)
    __shared__ bf16 Vt[32][424];      // V transposed
    __shared__ bf16 Pb[8][2][16][40]; // per-wave, 2 rotating P buffers

    const int tid = threadIdx.x;
    const int win = blockIdx.x >> 2, head = blockIdx.x & 3;
    const int wi = win & 127;
    const int wt_i = wi >> 6, wh_i = (wi >> 3) & 7, ww_i = wi & 7;
    const int pat = ((wt_i == 1) << 2) | ((wh_i == 7) << 1) | (ww_i == 7);

    const bf16* Qg = qws + (size_t)(win * NHc + head) * VOL * HDc;
    const bf16* Kg = kws + (size_t)(win * NHc + head) * VOL * HDc;
    const bf16* Vg = vws + (size_t)(win * NHc + head) * VOL * HDc;
    const bf16* Bg = bmt + (size_t)(pat * NHc + head) * 400 * 416;

    for (int idx = tid; idx < 400 * 4; idx += 512) {
        int tok = idx >> 2, c = idx & 3;
        bf16x8 v = zero8();
        if (tok < VOL) v = *(const bf16x8*)(Kg + tok * HDc + c * 8);
        *(bf16x8*)(&Kl[tok][c * 8]) = v;
    }
    if (tid < 416) {  // V transpose: b64 chunks of 4 toks
        int c = tid & 3, tok4 = (tid >> 2) * 4;
        bf16x8 rr[4];
#pragma unroll
        for (int i = 0; i < 4; ++i)
            rr[i] = (tok4 + i < VOL) ? *(const bf16x8*)(Vg + (tok4 + i) * HDc + c * 8) : zero8();
#pragma unroll
        for (int j = 0; j < 8; ++j) {
            bf16x4 wv;
            wv[0] = rr[0][j]; wv[1] = rr[1][j]; wv[2] = rr[2][j]; wv[3] = rr[3][j];
            *(bf16x4*)(&Vt[c * 8 + j][tok4]) = wv;
        }
    }
    __syncthreads();

    const int wid = tid >> 6, lane = tid & 63;
    const int quad = lane >> 4, l15 = lane & 15;
    bf16* Pw0 = &Pb[wid][0][0][0];
    bf16* Pw1 = &Pb[wid][1][0][0];
    const bool hasD = (wid == 0);

    // stream q-tile bases: A,B,C rows all < 384 (no clamp); D rows 384..399.
    const int qbA = wid * 16, qbB = qbA + 128, qbC = qbA + 256, qbD = 384;
    const bf16x8 qfA = *(const bf16x8*)(Qg + (size_t)(qbA + l15) * HDc + quad * 8);
    const bf16x8 qfB = *(const bf16x8*)(Qg + (size_t)(qbB + l15) * HDc + quad * 8);
    const bf16x8 qfC = *(const bf16x8*)(Qg + (size_t)(qbC + l15) * HDc + quad * 8);
    bf16x8 qfD;
    const int brA = (qbA + l15) * 416, brB = (qbB + l15) * 416;
    const int brC = (qbC + l15) * 416, brD = (qbD + l15) * 416;

    f32x4 oA0 = zf4(), oA1 = zf4(), oB0 = zf4(), oB1 = zf4();
    f32x4 oC0 = zf4(), oC1 = zf4(), oD0 = zf4(), oD1 = zf4();
    float lsA = 0.f, lsB = 0.f, lsC = 0.f, lsD = 0.f;

    bf16x4 nbA0 = *(const bf16x4*)(Bg + brA + quad * 4);
    bf16x4 nbA1 = *(const bf16x4*)(Bg + brA + 16 + quad * 4);
    bf16x4 nbB0 = *(const bf16x4*)(Bg + brB + quad * 4);
    bf16x4 nbB1 = *(const bf16x4*)(Bg + brB + 16 + quad * 4);
    bf16x4 nbC0 = *(const bf16x4*)(Bg + brC + quad * 4);
    bf16x4 nbC1 = *(const bf16x4*)(Bg + brC + 16 + quad * 4);
    bf16x4 nbD0, nbD1;
    if (hasD) {
        int qrD = qbD + l15; if (qrD >= VOL) qrD = VOL - 1;
        qfD = *(const bf16x8*)(Qg + (size_t)qrD * HDc + quad * 8);
        nbD0 = *(const bf16x4*)(Bg + brD + quad * 4);
        nbD1 = *(const bf16x4*)(Bg + brD + 16 + quad * 4);
    }

    // full 32-k tile: S^T MFMA pair + exp2 + P write; prefetch bias one kt ahead
    auto qk = [&](const bf16x8& kf0, const bf16x8& kf1, const bf16x8& qf,
                  bf16x4& nb0, bf16x4& nb1, int br, float& ls, bf16* Pw, int kb) {
        f32x4 c0 = up4(nb0), c1 = up4(nb1);
        if (kb < 384) {
            nb0 = *(const bf16x4*)(Bg + br + kb + 32 + quad * 4);
            nb1 = *(const bf16x4*)(Bg + br + kb + 48 + quad * 4);
        }
        f32x4 s0 = MFMA(kf0, qf, c0);
        f32x4 s1 = MFMA(kf1, qf, c1);
        bf16x4 p0, p1;
        float la = 0.f;
#pragma unroll
        for (int r = 0; r < 4; ++r) {
            float e0 = __builtin_amdgcn_exp2f(s0[r]);
            float e1 = __builtin_amdgcn_exp2f(s1[r]);
            p0[r] = (bf16)e0; p1[r] = (bf16)e1; la += e0 + e1;
        }
        ls += la;
        *(bf16x4*)(Pw + l15 * 40 + quad * 4) = p0;
        *(bf16x4*)(Pw + l15 * 40 + 16 + quad * 4) = p1;
    };
    // kt12 half-tile: only k 384..399 real; second half of P zeroed
    auto qkh = [&](const bf16x8& kf0, const bf16x8& qf, bf16x4& nb0, float& ls, bf16* Pw) {
        f32x4 c0 = up4(nb0);
        f32x4 s0 = MFMA(kf0, qf, c0);
        bf16x4 p0, z4;
        float la = 0.f;
#pragma unroll
        for (int r = 0; r < 4; ++r) {
            float e0 = __builtin_amdgcn_exp2f(s0[r]);
            p0[r] = (bf16)e0; la += e0; z4[r] = (bf16)0.f;
        }
        ls += la;
        *(bf16x4*)(Pw + l15 * 40 + quad * 4) = p0;
        *(bf16x4*)(Pw + l15 * 40 + 16 + quad * 4) = z4;
    };
    auto pv = [&](bf16* Pw, const bf16x8& vf0, const bf16x8& vf1, f32x4& o0, f32x4& o1) {
        bf16x8 pf = *(const bf16x8*)(Pw + l15 * 40 + quad * 8);
        o0 = MFMA(vf0, pf, o0);
        o1 = MFMA(vf1, pf, o1);
    };

#pragma unroll 1
    for (int kt = 0; kt < 12; ++kt) {
        const int kb = kt * 32;
        bf16x8 kf0 = *(const bf16x8*)(&Kl[kb + l15][quad * 8]);
        bf16x8 kf1 = *(const bf16x8*)(&Kl[kb + 16 + l15][quad * 8]);
        bf16x8 vf0 = *(const bf16x8*)(&Vt[l15][kb + quad * 8]);
        bf16x8 vf1 = *(const bf16x8*)(&Vt[16 + l15][kb + quad * 8]);
        qk(kf0, kf1, qfA, nbA0, nbA1, brA, lsA, Pw0, kb);
        qk(kf0, kf1, qfB, nbB0, nbB1, brB, lsB, Pw1, kb);
        pv(Pw0, vf0, vf1, oA0, oA1);
        qk(kf0, kf1, qfC, nbC0, nbC1, brC, lsC, Pw0, kb);
        pv(Pw1, vf0, vf1, oB0, oB1);
        if (hasD) qk(kf0, kf1, qfD, nbD0, nbD1, brD, lsD, Pw1, kb);
        pv(Pw0, vf0, vf1, oC0, oC1);
        if (hasD) pv(Pw1, vf0, vf1, oD0, oD1);
    }
    {   // kt = 12 (kb=384): half-tile
        bf16x8 kf0 = *(const bf16x8*)(&Kl[384 + l15][quad * 8]);
        bf16x8 vf0 = *(const bf16x8*)(&Vt[l15][384 + quad * 8]);
        bf16x8 vf1 = *(const bf16x8*)(&Vt[16 + l15][384 + quad * 8]);
        qkh(kf0, qfA, nbA0, lsA, Pw0);
        qkh(kf0, qfB, nbB0, lsB, Pw1);
        pv(Pw0, vf0, vf1, oA0, oA1);
        qkh(kf0, qfC, nbC0, lsC, Pw0);
        pv(Pw1, vf0, vf1, oB0, oB1);
        if (hasD) qkh(kf0, qfD, nbD0, lsD, Pw1);
        pv(Pw0, vf0, vf1, oC0, oC1);
        if (hasD) pv(Pw1, vf0, vf1, oD0, oD1);
    }

    auto fin = [&](float ls, const f32x4& o0, const f32x4& o1, int qb) {
        ls += __shfl_xor(ls, 16); ls += __shfl_xor(ls, 32);
        if (qb + l15 < VOL) {
            float inv = 1.f / ls;
            bf16x4 w0, w1;
#pragma unroll
            for (int r = 0; r < 4; ++r) { w0[r] = (bf16)(o0[r] * inv); w1[r] = (bf16)(o1[r] * inv); }
            bf16* dst = aows + ((size_t)win * VOL + qb + l15) * Cc + head * HDc;
            *(bf16x4*)(dst + quad * 4) = w0;
            *(bf16x4*)(dst + 16 + quad * 4) = w1;
        }
    };
    fin(lsA, oA0, oA1, qbA);
    fin(lsB, oB0, oB1, qbB);
    fin(lsC, oC0, oC1, qbC);
    if (hasD) fin(lsD, oD0, oD1, qbD);
}

// ---------------------------------------------------------------------------
// Kernel 3: output projection (C^T epilogue: f32x4 b128 LDS writes) +
// un-partition + roll-back scatter, fp32 out.
// ---------------------------------------------------------------------------
__global__ __launch_bounds__(256, 2)
void proj_kernel(const bf16* __restrict__ aows, const bf16* __restrict__ wp,
                 const bf16* __restrict__ bp, float* __restrict__ out) {
    __shared__ bf16 As[64][136];
    __shared__ float Csf[64][132];
    __shared__ unsigned int rbo[64];
    const int tid = threadIdx.x;
    const int m0 = blockIdx.x * 64;

    if (tid < 64) {
        int g = m0 + tid;
        int win = g / VOL, tok = g % VOL;
        int b = win >> 7, wi = win & 127;
        int wt_i = wi >> 6, wh_i = (wi >> 3) & 7, ww_i = wi & 7;
        int tt = tok / 49, r2 = tok % 49, hh = r2 / 7, ww2 = r2 % 7;
        int t = wt_i * 8 + tt + STc; if (t >= Tc) t -= Tc;
        int h = wh_i * 7 + hh + SHc; if (h >= Hc) h -= Hc;
        int w = ww_i * 7 + ww2 + SWc; if (w >= Wc) w -= Wc;
        rbo[tid] = (unsigned int)((((b * Tc + t) * Hc + h) * Wc + w) * Cc * 4);
    }
    for (int idx = tid; idx < 64 * 16; idx += 256) {
        int r = idx >> 4, c = idx & 15;
        *(bf16x8*)(&As[r][c * 8]) = *(const bf16x8*)(aows + (size_t)(m0 + r) * Cc + c * 8);
    }
    __syncthreads();

    const int wid = tid >> 6, lane = tid & 63;
    const int quad = lane >> 4, l15 = lane & 15;

    f32x4 acc[8];  // mt over 128 output cols; rows = wid*16..+15
#pragma unroll
    for (int mt = 0; mt < 8; ++mt) acc[mt] = zf4();

#pragma unroll
    for (int ko = 0; ko < 4; ++ko) {
        bf16x8 xf = *(const bf16x8*)(&As[wid * 16 + l15][ko * 32 + quad * 8]);
#pragma unroll
        for (int mt = 0; mt < 8; ++mt) {
            bf16x8 wf = *(const bf16x8*)(wp + (size_t)(mt * 16 + l15) * Cc + ko * 32 + quad * 8);
            acc[mt] = MFMA(wf, xf, acc[mt]);  // C^T: m=col, n=row
        }
    }
#pragma unroll
    for (int mt = 0; mt < 8; ++mt) {
        int colbase = mt * 16 + quad * 4;
        bf16x4 bc = *(const bf16x4*)(bp + colbase);
        f32x4 o;
#pragma unroll
        for (int r = 0; r < 4; ++r) o[r] = acc[mt][r] + (float)bc[r];
        *(f32x4*)(&Csf[wid * 16 + l15][colbase]) = o;
    }
    __syncthreads();

    for (int idx = tid; idx < 64 * 32; idx += 256) {
        int row = idx >> 5, ch = idx & 31;
        float* dst = (float*)((char*)out + rbo[row]) + ch * 4;
        *(f32x4*)dst = *(const f32x4*)(&Csf[row][ch * 4]);
    }
}

extern "C" void kernel_launch(void* const* d_in, const int* in_sizes, int n_in,
                              void* d_out, int out_size, void* d_ws, size_t ws_size,
                              hipStream_t stream) {
    const float* x    = (const float*)d_in[0];
    const float* wqf  = (const float*)d_in[1];
    const float* bqf  = (const float*)d_in[2];
    const float* wpf  = (const float*)d_in[3];
    const float* bpf  = (const float*)d_in[4];
    const float* rpbf = (const float*)d_in[5];
    float* out = (float*)d_out;

    bf16* wqb  = (bf16*)d_ws;              // 49152
    bf16* bqb  = wqb + 49152;              // 384
    bf16* wpb  = bqb + 384;                // 16384
    bf16* bpb  = wpb + 16384;              // 128
    bf16* bmt  = bpb + 128;                // BMT_N = 5,324,800
    bf16* qws  = bmt + BMT_N;
    bf16* kws  = qws + QSZ;
    bf16* vws  = kws + QSZ;
    bf16* aows = vws + QSZ;

    hipLaunchKernelGGL(prep_kernel, dim3(865), dim3(256), 0, stream,
                       wqf, bqf, wpf, bpf, rpbf, wqb, bqb, wpb, bpb, bmt);
    hipLaunchKernelGGL(qkv_kernel, dim3(MTOT / 64), dim3(256), 0, stream,
                       x, wqb, bqb, qws, kws, vws);
    hipLaunchKernelGGL(attn_kernel, dim3(TWIN * NHc), dim3(512), 0, stream,
                       qws, kws, vws, bmt, aows);
    hipLaunchKernelGGL(proj_kernel, dim3(MTOT / 64), dim3(256), 0, stream,
                       aows, wpb, bpb, out);
}

// Round 11
// 259.724 us; speedup vs baseline: 1.0692x; 1.0019x over previous
//
#include <hip/hip_runtime.h>
#include <hip/hip_bf16.h>

typedef __bf16 bf16;
typedef __bf16 bf16x4 __attribute__((ext_vector_type(4)));
typedef __bf16 bf16x8 __attribute__((ext_vector_type(8)));
typedef float f32x4 __attribute__((ext_vector_type(4)));

#define MFMA(a, b, c) __builtin_amdgcn_mfma_f32_16x16x32_bf16(a, b, c, 0, 0, 0)

__device__ inline f32x4 zf4() { return f32x4{0.f, 0.f, 0.f, 0.f}; }

constexpr int Tc = 16, Hc = 56, Wc = 56, Cc = 128, NHc = 4, HDc = 32;
constexpr int VOL = 392;                 // 8*7*7 tokens per window
constexpr int STc = 4, SHc = 3, SWc = 3; // shift
constexpr int TWIN = 256;                // total windows (B * 128)
constexpr int MTOT = TWIN * VOL;         // 100352 tokens
constexpr int QSZ = TWIN * NHc * VOL * HDc;
constexpr int BMT_N = 8 * 4 * 400 * 416; // [pat][head][row][col] bias+mask table

__device__ inline bf16x8 zero8() {
    bf16x8 z;
#pragma unroll
    for (int j = 0; j < 8; ++j) z[j] = (bf16)0.0f;
    return z;
}

__device__ inline f32x4 up4(bf16x4 b) {
    f32x4 r;
#pragma unroll
    for (int j = 0; j < 4; ++j) r[j] = (float)b[j];
    return r;
}

__device__ inline int cls_of(int v, int pt, int ph, int pw) {
    int tt = v / 49, rem = v % 49, hh = rem / 7, ww = rem % 7;
    int ct = pt ? (tt < 4 ? 1 : 2) : 0;
    int ch = ph ? (hh < 4 ? 1 : 2) : 0;
    int cw = pw ? (ww < 4 ? 1 : 2) : 0;
    return ct * 9 + ch * 3 + cw;
}

// ---------------------------------------------------------------------------
// Kernel 0: fused prep. Blocks 0..64: fp32->bf16 param cvt.
// Blocks 65..864: bias+mask table bmt[pat8][head4][row400][col416] bf16 =
//   (rpb + mask)*log2e; pad col -> -144 (exp2 ~ 0), pad row -> 0.
// ---------------------------------------------------------------------------
__global__ void prep_kernel(const float* __restrict__ wq, const float* __restrict__ bq,
                            const float* __restrict__ wp, const float* __restrict__ bp,
                            const float* __restrict__ rpb,
                            bf16* __restrict__ wqb, bf16* __restrict__ bqb,
                            bf16* __restrict__ wpb, bf16* __restrict__ bpb,
                            bf16* __restrict__ bmt) {
    const int blk = blockIdx.x, tid = threadIdx.x;
    if (blk < 65) {
        int i = blk * 256 + tid;
        const float* s; bf16* d; int off;
        if (i < 12288)       { s = wq; d = wqb; off = i; }
        else if (i < 12384)  { s = bq; d = bqb; off = i - 12288; }
        else if (i < 16480)  { s = wp; d = wpb; off = i - 12384; }
        else if (i < 16512)  { s = bp; d = bpb; off = i - 16480; }
        else return;
        f32x4 v = *(const f32x4*)(s + (size_t)off * 4);
        bf16x4 o;
#pragma unroll
        for (int j = 0; j < 4; ++j) o[j] = (bf16)v[j];
        *(bf16x4*)(d + (size_t)off * 4) = o;
        return;
    }
    // bias blocks: bb = (pat, head, rowchunk of 16)
    __shared__ unsigned char clsc[392];
    int bb = blk - 65;
    int pat = bb / 100, rem = bb % 100;
    int head = rem / 25, rc = rem % 25;
    int pt = (pat >> 2) & 1, ph = (pat >> 1) & 1, pw = pat & 1;
    for (int v = tid; v < 392; v += 256) clsc[v] = (unsigned char)cls_of(v, pt, ph, pw);
    __syncthreads();
    bf16* dst = bmt + ((size_t)(pat * NHc + head) * 400 + rc * 16) * 416;
    for (int idx = tid; idx < 16 * 104; idx += 256) {
        int lr = idx / 104, c4 = idx % 104;
        int row = rc * 16 + lr;
        bf16x4 o;
        if (row >= VOL) {
#pragma unroll
            for (int j = 0; j < 4; ++j) o[j] = (bf16)0.f;
        } else {
            int rcls = clsc[row];
            const float* brow = rpb + (size_t)(head * VOL + row) * VOL;
#pragma unroll
            for (int j = 0; j < 4; ++j) {
                int col = c4 * 4 + j;
                float v;
                if (col >= VOL) v = -144.0f;
                else {
                    v = brow[col] * 1.4426950408889634f;
                    if (clsc[col] != rcls) v -= 144.0f;
                }
                o[j] = (bf16)v;
            }
        }
        *(bf16x4*)(dst + (size_t)lr * 416 + c4 * 4) = o;
    }
}

// ---------------------------------------------------------------------------
// Kernel 1: QKV projection (roll+partition fused gather, C^T-layout epilogue).
// Epilogue split into two 192-col phases -> LDS 44 KB -> 3 blocks/CU.
// (4 blocks/CU spills/thrashes; 3 is the sweet spot.)
// q pre-scaled by log2(e)/sqrt(32).
// ---------------------------------------------------------------------------
__global__ __launch_bounds__(256, 3)
void qkv_kernel(const float* __restrict__ x, const bf16* __restrict__ wq,
                const bf16* __restrict__ bq, bf16* __restrict__ qws,
                bf16* __restrict__ kws, bf16* __restrict__ vws) {
    __shared__ bf16 As[64][136];
    __shared__ bf16 Cs[64][204];   // 204: 8B-aligned rows (408B), 192 cols + pad
    __shared__ unsigned int rb[64];
    __shared__ unsigned int rbw[64];
    const int tid = threadIdx.x;
    const int m0 = blockIdx.x * 64;

    if (tid < 64) {
        int g = m0 + tid;
        int win = g / VOL, tok = g % VOL;
        int b = win >> 7, wi = win & 127;
        int wt_i = wi >> 6, wh_i = (wi >> 3) & 7, ww_i = wi & 7;
        int tt = tok / 49, r2 = tok % 49, hh = r2 / 7, ww2 = r2 % 7;
        int t = wt_i * 8 + tt + STc; if (t >= Tc) t -= Tc;
        int h = wh_i * 7 + hh + SHc; if (h >= Hc) h -= Hc;
        int w = ww_i * 7 + ww2 + SWc; if (w >= Wc) w -= Wc;
        rb[tid] = (unsigned int)((((b * Tc + t) * Hc + h) * Wc + w) * Cc * 4);
        rbw[tid] = (unsigned int)((win << 9) | tok);
    }
    __syncthreads();

    for (int idx = tid; idx < 64 * 32; idx += 256) {
        int r = idx >> 5, c = idx & 31;
        const float* src = (const float*)((const char*)x + rb[r]) + c * 4;
        f32x4 v = *(const f32x4*)src;
        bf16x4 o;
#pragma unroll
        for (int j = 0; j < 4; ++j) o[j] = (bf16)v[j];
        *(bf16x4*)(&As[r][c * 4]) = o;
    }
    __syncthreads();

    const int wid = tid >> 6, lane = tid & 63;
    const int quad = lane >> 4, l15 = lane & 15;
    const int nbase = wid * 96;

    f32x4 acc[6][4];  // [mt = W-col tile][nt = row tile]
#pragma unroll
    for (int mt = 0; mt < 6; ++mt)
#pragma unroll
        for (int nt = 0; nt < 4; ++nt) acc[mt][nt] = zf4();

#pragma unroll
    for (int ko = 0; ko < 4; ++ko) {
        bf16x8 xf[4];  // B-operand: x rows
#pragma unroll
        for (int nt = 0; nt < 4; ++nt)
            xf[nt] = *(const bf16x8*)(&As[nt * 16 + l15][ko * 32 + quad * 8]);
#pragma unroll
        for (int mt = 0; mt < 6; ++mt) {
            bf16x8 wf = *(const bf16x8*)(wq + (size_t)(nbase + mt * 16 + l15) * Cc + ko * 32 + quad * 8);
#pragma unroll
            for (int nt = 0; nt < 4; ++nt)
                acc[mt][nt] = MFMA(wf, xf[nt], acc[mt][nt]);  // C^T: m=col, n=row
        }
    }

    // Two-phase epilogue: phase 0 = cols [0,192) (waves 0,1), phase 1 = [192,384).
#pragma unroll 1
    for (int phase = 0; phase < 2; ++phase) {
        if ((wid >> 1) == phase) {
#pragma unroll
            for (int mt = 0; mt < 6; ++mt) {
                int colbase = nbase + mt * 16 + quad * 4;
                int lc = colbase - phase * 192;   // in [0,192)
                bf16x4 bc = *(const bf16x4*)(bq + colbase);
                float scale = (colbase < 128) ? 0.25505653942f : 1.0f;  // log2e/sqrt(32) on q
#pragma unroll
                for (int nt = 0; nt < 4; ++nt) {
                    bf16x4 o;
#pragma unroll
                    for (int r = 0; r < 4; ++r)
                        o[r] = (bf16)((acc[mt][nt][r] + (float)bc[r]) * scale);
                    *(bf16x4*)(&Cs[nt * 16 + l15][lc]) = o;
                }
            }
        }
        __syncthreads();
        // store 64 rows x 6 head-slices of 32 cols each (same global pattern as r0)
        for (int u = tid; u < 64 * 6; u += 256) {
            int row = u / 6, s = u - row * 6;
            int gs = phase * 6 + s;   // 0..3 q.h, 4..7 k.h, 8..11 v.h
            bf16* basep = (gs < 4) ? qws : (gs < 8) ? kws : vws;
            int head = gs & 3;
            unsigned int p = rbw[row];
            int win = p >> 9, tok = p & 511;
            size_t off = ((size_t)(win * NHc + head) * VOL + tok) * HDc;
#pragma unroll
            for (int c = 0; c < 4; ++c) {
                bf16x4 lo = *(const bf16x4*)(&Cs[row][s * 32 + c * 8]);
                bf16x4 hi = *(const bf16x4*)(&Cs[row][s * 32 + c * 8 + 4]);
                *(bf16x8*)(basep + off + c * 8) = __builtin_shufflevector(lo, hi, 0, 1, 2, 3, 4, 5, 6, 7);
            }
        }
        __syncthreads();
    }
}

// ---------------------------------------------------------------------------
// Kernel 2: windowed attention, S^T formulation, pattern bias table.
// SINGLE k-sweep, 4 q-tile streams per wave. Launch bounds (512,2): VGPR cap
// 128 (the (512,4) variant capped at 64 and spilled). LDS 79.9KB -> 2 blk/CU.
// ---------------------------------------------------------------------------
__global__ __launch_bounds__(512, 2)
void attn_kernel(const bf16* __restrict__ qws, const bf16* __restrict__ kws,
                 const bf16* __restrict__ vws, const bf16* __restrict__ bmt,
                 bf16* __restrict__ aows) {
    __shared__ bf16 Kl[400][40];      // rows 392..399 zero (kt12 is half-tile)
    __shared__ bf16 Vt[32][424];      // V transposed
    __shared__ bf16 Pb[8][2][16][40]; // per-wave, 2 rotating P buffers

    const int tid = threadIdx.x;
    const int win = blockIdx.x >> 2, head = blockIdx.x & 3;
    const int wi = win & 127;
    const int wt_i = wi >> 6, wh_i = (wi >> 3) & 7, ww_i = wi & 7;
    const int pat = ((wt_i == 1) << 2) | ((wh_i == 7) << 1) | (ww_i == 7);

    const bf16* Qg = qws + (size_t)(win * NHc + head) * VOL * HDc;
    const bf16* Kg = kws + (size_t)(win * NHc + head) * VOL * HDc;
    const bf16* Vg = vws + (size_t)(win * NHc + head) * VOL * HDc;
    const bf16* Bg = bmt + (size_t)(pat * NHc + head) * 400 * 416;

    for (int idx = tid; idx < 400 * 4; idx += 512) {
        int tok = idx >> 2, c = idx & 3;
        bf16x8 v = zero8();
        if (tok < VOL) v = *(const bf16x8*)(Kg + tok * HDc + c * 8);
        *(bf16x8*)(&Kl[tok][c * 8]) = v;
    }
    if (tid < 416) {  // V transpose: b64 chunks of 4 toks
        int c = tid & 3, tok4 = (tid >> 2) * 4;
        bf16x8 rr[4];
#pragma unroll
        for (int i = 0; i < 4; ++i)
            rr[i] = (tok4 + i < VOL) ? *(const bf16x8*)(Vg + (tok4 + i) * HDc + c * 8) : zero8();
#pragma unroll
        for (int j = 0; j < 8; ++j) {
            bf16x4 wv;
            wv[0] = rr[0][j]; wv[1] = rr[1][j]; wv[2] = rr[2][j]; wv[3] = rr[3][j];
            *(bf16x4*)(&Vt[c * 8 + j][tok4]) = wv;
        }
    }
    __syncthreads();

    const int wid = tid >> 6, lane = tid & 63;
    const int quad = lane >> 4, l15 = lane & 15;
    bf16* Pw0 = &Pb[wid][0][0][0];
    bf16* Pw1 = &Pb[wid][1][0][0];
    const bool hasD = (wid == 0);

    // stream q-tile bases: A,B,C rows all < 384 (no clamp); D rows 384..399.
    const int qbA = wid * 16, qbB = qbA + 128, qbC = qbA + 256, qbD = 384;
    const bf16x8 qfA = *(const bf16x8*)(Qg + (size_t)(qbA + l15) * HDc + quad * 8);
    const bf16x8 qfB = *(const bf16x8*)(Qg + (size_t)(qbB + l15) * HDc + quad * 8);
    const bf16x8 qfC = *(const bf16x8*)(Qg + (size_t)(qbC + l15) * HDc + quad * 8);
    bf16x8 qfD;
    const int brA = (qbA + l15) * 416, brB = (qbB + l15) * 416;
    const int brC = (qbC + l15) * 416, brD = (qbD + l15) * 416;

    f32x4 oA0 = zf4(), oA1 = zf4(), oB0 = zf4(), oB1 = zf4();
    f32x4 oC0 = zf4(), oC1 = zf4(), oD0 = zf4(), oD1 = zf4();
    float lsA = 0.f, lsB = 0.f, lsC = 0.f, lsD = 0.f;

    bf16x4 nbA0 = *(const bf16x4*)(Bg + brA + quad * 4);
    bf16x4 nbA1 = *(const bf16x4*)(Bg + brA + 16 + quad * 4);
    bf16x4 nbB0 = *(const bf16x4*)(Bg + brB + quad * 4);
    bf16x4 nbB1 = *(const bf16x4*)(Bg + brB + 16 + quad * 4);
    bf16x4 nbC0 = *(const bf16x4*)(Bg + brC + quad * 4);
    bf16x4 nbC1 = *(const bf16x4*)(Bg + brC + 16 + quad * 4);
    bf16x4 nbD0, nbD1;
    if (hasD) {
        int qrD = qbD + l15; if (qrD >= VOL) qrD = VOL - 1;
        qfD = *(const bf16x8*)(Qg + (size_t)qrD * HDc + quad * 8);
        nbD0 = *(const bf16x4*)(Bg + brD + quad * 4);
        nbD1 = *(const bf16x4*)(Bg + brD + 16 + quad * 4);
    }

    // full 32-k tile: S^T MFMA pair + exp2 + P write; prefetch bias one kt ahead
    auto qk = [&](const bf16x8& kf0, const bf16x8& kf1, const bf16x8& qf,
                  bf16x4& nb0, bf16x4& nb1, int br, float& ls, bf16* Pw, int kb) {
        f32x4 c0 = up4(nb0), c1 = up4(nb1);
        if (kb < 384) {
            nb0 = *(const bf16x4*)(Bg + br + kb + 32 + quad * 4);
            nb1 = *(const bf16x4*)(Bg + br + kb + 48 + quad * 4);
        }
        f32x4 s0 = MFMA(kf0, qf, c0);
        f32x4 s1 = MFMA(kf1, qf, c1);
        bf16x4 p0, p1;
        float la = 0.f;
#pragma unroll
        for (int r = 0; r < 4; ++r) {
            float e0 = __builtin_amdgcn_exp2f(s0[r]);
            float e1 = __builtin_amdgcn_exp2f(s1[r]);
            p0[r] = (bf16)e0; p1[r] = (bf16)e1; la += e0 + e1;
        }
        ls += la;
        *(bf16x4*)(Pw + l15 * 40 + quad * 4) = p0;
        *(bf16x4*)(Pw + l15 * 40 + 16 + quad * 4) = p1;
    };
    // kt12 half-tile: only k 384..399 real; second half of P zeroed
    auto qkh = [&](const bf16x8& kf0, const bf16x8& qf, bf16x4& nb0, float& ls, bf16* Pw) {
        f32x4 c0 = up4(nb0);
        f32x4 s0 = MFMA(kf0, qf, c0);
        bf16x4 p0, z4;
        float la = 0.f;
#pragma unroll
        for (int r = 0; r < 4; ++r) {
            float e0 = __builtin_amdgcn_exp2f(s0[r]);
            p0[r] = (bf16)e0; la += e0; z4[r] = (bf16)0.f;
        }
        ls += la;
        *(bf16x4*)(Pw + l15 * 40 + quad * 4) = p0;
        *(bf16x4*)(Pw + l15 * 40 + 16 + quad * 4) = z4;
    };
    auto pv = [&](bf16* Pw, const bf16x8& vf0, const bf16x8& vf1, f32x4& o0, f32x4& o1) {
        bf16x8 pf = *(const bf16x8*)(Pw + l15 * 40 + quad * 8);
        o0 = MFMA(vf0, pf, o0);
        o1 = MFMA(vf1, pf, o1);
    };

#pragma unroll 1
    for (int kt = 0; kt < 12; ++kt) {
        const int kb = kt * 32;
        bf16x8 kf0 = *(const bf16x8*)(&Kl[kb + l15][quad * 8]);
        bf16x8 kf1 = *(const bf16x8*)(&Kl[kb + 16 + l15][quad * 8]);
        bf16x8 vf0 = *(const bf16x8*)(&Vt[l15][kb + quad * 8]);
        bf16x8 vf1 = *(const bf16x8*)(&Vt[16 + l15][kb + quad * 8]);
        qk(kf0, kf1, qfA, nbA0, nbA1, brA, lsA, Pw0, kb);
        qk(kf0, kf1, qfB, nbB0, nbB1, brB, lsB, Pw1, kb);
        pv(Pw0, vf0, vf1, oA0, oA1);
        qk(kf0, kf1, qfC, nbC0, nbC1, brC, lsC, Pw0, kb);
        pv(Pw1, vf0, vf1, oB0, oB1);
        if (hasD) qk(kf0, kf1, qfD, nbD0, nbD1, brD, lsD, Pw1, kb);
        pv(Pw0, vf0, vf1, oC0, oC1);
        if (hasD) pv(Pw1, vf0, vf1, oD0, oD1);
    }
    {   // kt = 12 (kb=384): half-tile
        bf16x8 kf0 = *(const bf16x8*)(&Kl[384 + l15][quad * 8]);
        bf16x8 vf0 = *(const bf16x8*)(&Vt[l15][384 + quad * 8]);
        bf16x8 vf1 = *(const bf16x8*)(&Vt[16 + l15][384 + quad * 8]);
        qkh(kf0, qfA, nbA0, lsA, Pw0);
        qkh(kf0, qfB, nbB0, lsB, Pw1);
        pv(Pw0, vf0, vf1, oA0, oA1);
        qkh(kf0, qfC, nbC0, lsC, Pw0);
        pv(Pw1, vf0, vf1, oB0, oB1);
        if (hasD) qkh(kf0, qfD, nbD0, lsD, Pw1);
        pv(Pw0, vf0, vf1, oC0, oC1);
        if (hasD) pv(Pw1, vf0, vf1, oD0, oD1);
    }

    auto fin = [&](float ls, const f32x4& o0, const f32x4& o1, int qb) {
        ls += __shfl_xor(ls, 16); ls += __shfl_xor(ls, 32);
        if (qb + l15 < VOL) {
            float inv = 1.f / ls;
            bf16x4 w0, w1;
#pragma unroll
            for (int r = 0; r < 4; ++r) { w0[r] = (bf16)(o0[r] * inv); w1[r] = (bf16)(o1[r] * inv); }
            bf16* dst = aows + ((size_t)win * VOL + qb + l15) * Cc + head * HDc;
            *(bf16x4*)(dst + quad * 4) = w0;
            *(bf16x4*)(dst + 16 + quad * 4) = w1;
        }
    };
    fin(lsA, oA0, oA1, qbA);
    fin(lsB, oB0, oB1, qbB);
    fin(lsC, oC0, oC1, qbC);
    if (hasD) fin(lsD, oD0, oD1, qbD);
}

// ---------------------------------------------------------------------------
// Kernel 3: output projection (C^T epilogue: f32x4 b128 LDS writes) +
// un-partition + roll-back scatter, fp32 out. LDS 51.5 KB -> (256,3) gives
// 3 blocks/CU (mirrors the verified qkv (256,3) config; VGPR cap ~84 is
// enough for acc[8]=32 + operands).
// ---------------------------------------------------------------------------
__global__ __launch_bounds__(256, 3)
void proj_kernel(const bf16* __restrict__ aows, const bf16* __restrict__ wp,
                 const bf16* __restrict__ bp, float* __restrict__ out) {
    __shared__ bf16 As[64][136];
    __shared__ float Csf[64][132];
    __shared__ unsigned int rbo[64];
    const int tid = threadIdx.x;
    const int m0 = blockIdx.x * 64;

    if (tid < 64) {
        int g = m0 + tid;
        int win = g / VOL, tok = g % VOL;
        int b = win >> 7, wi = win & 127;
        int wt_i = wi >> 6, wh_i = (wi >> 3) & 7, ww_i = wi & 7;
        int tt = tok / 49, r2 = tok % 49, hh = r2 / 7, ww2 = r2 % 7;
        int t = wt_i * 8 + tt + STc; if (t >= Tc) t -= Tc;
        int h = wh_i * 7 + hh + SHc; if (h >= Hc) h -= Hc;
        int w = ww_i * 7 + ww2 + SWc; if (w >= Wc) w -= Wc;
        rbo[tid] = (unsigned int)((((b * Tc + t) * Hc + h) * Wc + w) * Cc * 4);
    }
    for (int idx = tid; idx < 64 * 16; idx += 256) {
        int r = idx >> 4, c = idx & 15;
        *(bf16x8*)(&As[r][c * 8]) = *(const bf16x8*)(aows + (size_t)(m0 + r) * Cc + c * 8);
    }
    __syncthreads();

    const int wid = tid >> 6, lane = tid & 63;
    const int quad = lane >> 4, l15 = lane & 15;

    f32x4 acc[8];  // mt over 128 output cols; rows = wid*16..+15
#pragma unroll
    for (int mt = 0; mt < 8; ++mt) acc[mt] = zf4();

#pragma unroll
    for (int ko = 0; ko < 4; ++ko) {
        bf16x8 xf = *(const bf16x8*)(&As[wid * 16 + l15][ko * 32 + quad * 8]);
#pragma unroll
        for (int mt = 0; mt < 8; ++mt) {
            bf16x8 wf = *(const bf16x8*)(wp + (size_t)(mt * 16 + l15) * Cc + ko * 32 + quad * 8);
            acc[mt] = MFMA(wf, xf, acc[mt]);  // C^T: m=col, n=row
        }
    }
#pragma unroll
    for (int mt = 0; mt < 8; ++mt) {
        int colbase = mt * 16 + quad * 4;
        bf16x4 bc = *(const bf16x4*)(bp + colbase);
        f32x4 o;
#pragma unroll
        for (int r = 0; r < 4; ++r) o[r] = acc[mt][r] + (float)bc[r];
        *(f32x4*)(&Csf[wid * 16 + l15][colbase]) = o;
    }
    __syncthreads();

    for (int idx = tid; idx < 64 * 32; idx += 256) {
        int row = idx >> 5, ch = idx & 31;
        float* dst = (float*)((char*)out + rbo[row]) + ch * 4;
        *(f32x4*)dst = *(const f32x4*)(&Csf[row][ch * 4]);
    }
}

extern "C" void kernel_launch(void* const* d_in, const int* in_sizes, int n_in,
                              void* d_out, int out_size, void* d_ws, size_t ws_size,
                              hipStream_t stream) {
    const float* x    = (const float*)d_in[0];
    const float* wqf  = (const float*)d_in[1];
    const float* bqf  = (const float*)d_in[2];
    const float* wpf  = (const float*)d_in[3];
    const float* bpf  = (const float*)d_in[4];
    const float* rpbf = (const float*)d_in[5];
    float* out = (float*)d_out;

    bf16* wqb  = (bf16*)d_ws;              // 49152
    bf16* bqb  = wqb + 49152;              // 384
    bf16* wpb  = bqb + 384;                // 16384
    bf16* bpb  = wpb + 16384;              // 128
    bf16* bmt  = bpb + 128;                // BMT_N = 5,324,800
    bf16* qws  = bmt + BMT_N;
    bf16* kws  = qws + QSZ;
    bf16* vws  = kws + QSZ;
    bf16* aows = vws + QSZ;

    hipLaunchKernelGGL(prep_kernel, dim3(865), dim3(256), 0, stream,
                       wqf, bqf, wpf, bpf, rpbf, wqb, bqb, wpb, bpb, bmt);
    hipLaunchKernelGGL(qkv_kernel, dim3(MTOT / 64), dim3(256), 0, stream,
                       x, wqb, bqb, qws, kws, vws);
    hipLaunchKernelGGL(attn_kernel, dim3(TWIN * NHc), dim3(512), 0, stream,
                       qws, kws, vws, bmt, aows);
    hipLaunchKernelGGL(proj_kernel, dim3(MTOT / 64), dim3(256), 0, stream,
                       aows, wpb, bpb, out);
}